// Round 4
// baseline (183.059 us; speedup 1.0000x reference)
//
#include <hip/hip_runtime.h>
#include <hip/hip_bf16.h>
#include <stdint.h>
#include <stddef.h>

// ContrastiveLoss: N=4096, D=768.
// loss = mean_{ij} (1-g)*d2 + g*max(2-sqrt(d2),0)^2,
// d2 = sa[i]+sb[j]-2*dot(i,j)+2e-6*(ra[i]-rb[j])+768e-12 (clamped at 0).
// R3: BK=32 double-buffered LDS, ONE barrier/iter (staging latency hidden
//     behind compute), cheap hinge-free epilogue fast path (exact slow path
//     guarded by min(d2) < 4, never taken for this data), XCD tile swizzle.

#define NROWS 4096
#define DIM   768
#define BM    128
#define BN    128
#define BK    32
#define KITERS (DIM / BK)   // 24
#define MARGIN 2.0f
#define EPSV   1e-6f

typedef __bf16 bf16_t;
typedef bf16_t bf16x8 __attribute__((ext_vector_type(8)));
typedef bf16_t bf16x4 __attribute__((ext_vector_type(4)));
typedef float  f32x4  __attribute__((ext_vector_type(4)));
typedef unsigned long long u64;

// ---------------- prologue: prep (2048 blocks) + pack (8192 blocks) --------
__global__ __launch_bounds__(256) void prologue_kernel(
    const float* __restrict__ A, const float* __restrict__ B,
    const int* __restrict__ gt,
    bf16_t* __restrict__ Ab, bf16_t* __restrict__ Bb,
    float* __restrict__ sa, float* __restrict__ sb,
    float* __restrict__ ra, float* __restrict__ rb,
    u64* __restrict__ gtp, float* __restrict__ out)
{
    const int tid  = threadIdx.x;
    const int wave = tid >> 6;
    const int lane = tid & 63;
    const int bx   = blockIdx.x;

    if (bx == 0 && tid == 0) out[0] = 0.0f;

    if (bx < 2048) {
        // ---- prep role: bf16 cast + exact fp32 row sums / sum-of-squares --
        const int isB  = bx >= 1024;
        const int row  = (bx & 1023) * 4 + wave;
        const float* X = isB ? B : A;
        bf16_t* Xb     = isB ? Bb : Ab;
        float* sdst    = isB ? sb : sa;
        float* rdst    = isB ? rb : ra;

        const float4* xr = (const float4*)(X + (size_t)row * DIM);
        bf16x4* xb = (bf16x4*)(Xb + (size_t)row * DIM);

        float sum = 0.0f, sq = 0.0f;
        #pragma unroll
        for (int j = 0; j < 3; ++j) {
            float4 v = xr[lane + 64 * j];
            bf16x4 o;
            o[0] = (bf16_t)v.x; o[1] = (bf16_t)v.y;
            o[2] = (bf16_t)v.z; o[3] = (bf16_t)v.w;
            xb[lane + 64 * j] = o;
            sum += (v.x + v.y) + (v.z + v.w);
            sq  += v.x * v.x + v.y * v.y + v.z * v.z + v.w * v.w;
        }
        #pragma unroll
        for (int off = 32; off > 0; off >>= 1) {
            sum += __shfl_down(sum, off);
            sq  += __shfl_down(sq,  off);
        }
        if (lane == 0) { rdst[row] = sum; sdst[row] = sq; }
    } else {
        // ---- pack role: gt int32 -> u64 bitmask per 64-col block ----------
        const int wid = (bx - 2048) * 4 + wave;
        const size_t base = (size_t)wid * 8;
        int v[8];
        #pragma unroll
        for (int i = 0; i < 8; ++i)
            v[i] = gt[base * 64 + (size_t)i * 64 + lane];
        u64 mine = 0;
        #pragma unroll
        for (int i = 0; i < 8; ++i) {
            const u64 m = __ballot(v[i] != 0);
            if (lane == i) mine = m;
        }
        if (lane < 8) gtp[base + lane] = mine;
    }
}

// ---------------- fused GEMM + loss ----------------------------------------
// 128x128 tile / 256 threads (4 waves x 64x64 of 4x4 16x16x32 MFMA).
// BK=32, double-buffered LDS (2x8KB per operand = 32 KB total), one
// __syncthreads per K-iter: stage(k+1) -> compute(k) -> barrier, so the
// compiler's vmcnt(0) drain at the barrier lands AFTER compute.
// XOR-4 swizzle: LDS chunk (row,p) holds global k-chunk p^(row&3)
// (b128 reads land 2-way max on banks = free per m136).
__global__ __launch_bounds__(256, 4) void loss_kernel(
    const bf16_t* __restrict__ A, const bf16_t* __restrict__ B,
    const float* __restrict__ sa, const float* __restrict__ sb,
    const float* __restrict__ ra, const float* __restrict__ rb,
    const uint2* __restrict__ gtp, float* __restrict__ out)
{
    __shared__ __align__(16) bf16_t As[2][BM * BK];  // 2 x 8 KB
    __shared__ __align__(16) bf16_t Bs[2][BN * BK];  // 2 x 8 KB

    const int tid  = threadIdx.x;
    const int wave = tid >> 6;
    const int lane = tid & 63;

    // XCD-aware tile swizzle: blocks round-robin across 8 XCDs by blockIdx;
    // give each XCD 4 contiguous tile-rows so its A-panel stays L2-resident.
    const int b    = blockIdx.x;
    const int xcd  = b & 7;
    const int slot = b >> 3;              // 0..127
    const int m0 = (xcd * 4 + (slot >> 5)) * BM;
    const int n0 = (slot & 31) * BN;

    f32x4 acc[4][4] = {};

    const int fr = lane & 15;            // frag row (A) / frag col (B)
    const int q  = lane >> 4;            // k-chunk 0..3
    const int wm = (wave >> 1) * 64;
    const int wn = (wave & 1) * 64;
    const int pos = (q ^ (fr & 3)) * 8;  // de-swizzled LDS k-slot (elements)

    // staging constants: chunk c -> row c>>2, LDS pos c&3 holds global
    // chunk (c&3)^(row&3)
    const int lrow0 = lane >> 2;         // relative row within 64-chunk span
    const int gcx   = (lane & 3) ^ (lrow0 & 3);

    auto stage = [&](int k0, int buf) {
        #pragma unroll
        for (int i = 0; i < 2; ++i) {
            const int c0   = wave * 64 + i * 256;   // wave-uniform chunk base
            const int row  = (c0 >> 2) + lrow0;     // this lane's tile row
            const bf16_t* ga = A + (size_t)(m0 + row) * DIM + k0 + gcx * 8;
            const bf16_t* gb = B + (size_t)(n0 + row) * DIM + k0 + gcx * 8;
            __builtin_amdgcn_global_load_lds(
                (const __attribute__((address_space(1))) void*)ga,
                (__attribute__((address_space(3))) void*)(&As[buf][c0 * 8]),
                16, 0, 0);
            __builtin_amdgcn_global_load_lds(
                (const __attribute__((address_space(1))) void*)gb,
                (__attribute__((address_space(3))) void*)(&Bs[buf][c0 * 8]),
                16, 0, 0);
        }
    };

    stage(0, 0);
    __syncthreads();                     // tile 0 ready (pipeline fill)

    for (int k = 0; k < KITERS; ++k) {
        const int buf = k & 1;
        if (k + 1 < KITERS) stage((k + 1) * BK, buf ^ 1);  // prefetch next

        bf16x8 af[4], bfr[4];
        #pragma unroll
        for (int i = 0; i < 4; ++i) {
            af[i]  = *(const bf16x8*)(&As[buf][(wm + i * 16 + fr) * BK + pos]);
            bfr[i] = *(const bf16x8*)(&Bs[buf][(wn + i * 16 + fr) * BK + pos]);
        }
        #pragma unroll
        for (int mi = 0; mi < 4; ++mi)
            #pragma unroll
            for (int ni = 0; ni < 4; ++ni)
                acc[mi][ni] = __builtin_amdgcn_mfma_f32_16x16x32_bf16(
                    af[mi], bfr[ni], acc[mi][ni], 0, 0, 0);

        __syncthreads();   // drains next-tile loads AFTER compute; protects buf reuse
    }

    // ---- epilogue: C/D layout col=lane&15, row=(lane>>4)*4+reg ----
    // contrib = (1-g)*max(d2,0) + g*max(2-sqrt(max(d2,0)),0)^2.
    // Fast path (valid when d2 >= 4, i.e. hinge == 0): contrib = d2 - g*d2.
    // Guard with running min(d2); exact slow path if any d2 < 4 (never here).
    const int cq = lane & 15;
    const int rq = (lane >> 4) * 4;
    const int cb = (n0 + wn) >> 6;

    float cc[4];
    #pragma unroll
    for (int ni = 0; ni < 4; ++ni) {
        const int col = n0 + wn + ni * 16 + cq;
        cc[ni] = sb[col] - 2.0f * EPSV * rb[col];
    }

    float s_all = 0.0f, s_g = 0.0f, dmin = 1e30f;
    #pragma unroll
    for (int mi = 0; mi < 4; ++mi) {
        #pragma unroll
        for (int rr = 0; rr < 4; ++rr) {
            const int row = m0 + wm + mi * 16 + rq + rr;
            const float crr = sa[row] + 2.0f * EPSV * ra[row]
                            + (float)DIM * EPSV * EPSV;
            const uint2 w = gtp[(size_t)row * (NROWS / 64) + cb];
            #pragma unroll
            for (int ni = 0; ni < 4; ++ni) {
                const float d2 = (crr + cc[ni]) - 2.0f * acc[mi][ni][rr];
                s_all += d2;
                dmin = fminf(dmin, d2);
                const unsigned wd = (ni < 2) ? w.x : w.y;
                const float gf = (float)((wd >> (cq + (ni & 1) * 16)) & 1u);
                s_g = fmaf(gf, d2, s_g);
            }
        }
    }
    float local = s_all - s_g;

    if (dmin < 4.0f) {   // exact correction; never taken for this data
        #pragma unroll
        for (int mi = 0; mi < 4; ++mi) {
            #pragma unroll
            for (int rr = 0; rr < 4; ++rr) {
                const int row = m0 + wm + mi * 16 + rq + rr;
                const float crr = sa[row] + 2.0f * EPSV * ra[row]
                                + (float)DIM * EPSV * EPSV;
                const uint2 w = gtp[(size_t)row * (NROWS / 64) + cb];
                #pragma unroll
                for (int ni = 0; ni < 4; ++ni) {
                    const float d2 = (crr + cc[ni]) - 2.0f * acc[mi][ni][rr];
                    if (d2 < 4.0f) {
                        const unsigned wd = (ni < 2) ? w.x : w.y;
                        const float gf = (float)((wd >> (cq + (ni & 1) * 16)) & 1u);
                        const float d2c  = fmaxf(d2, 0.0f);
                        const float dist = sqrtf(d2c);
                        const float h    = fmaxf(MARGIN - dist, 0.0f);
                        local += (1.0f - gf) * d2c + gf * h * h - (d2 - gf * d2);
                    }
                }
            }
        }
    }

    #pragma unroll
    for (int off = 32; off > 0; off >>= 1) local += __shfl_down(local, off);

    // reuse As as the 4-float block-reduction scratch (keeps LDS at 32 KB)
    float* redp = (float*)&As[0][0];
    __syncthreads();
    if (lane == 0) redp[wave] = local;
    __syncthreads();
    if (tid == 0) {
        const float s = (redp[0] + redp[1]) + (redp[2] + redp[3]);
        atomicAdd(out, s * (1.0f / (4096.0f * 4096.0f)));
    }
}

// ---------------------------------------------------------------------------
extern "C" void kernel_launch(void* const* d_in, const int* in_sizes, int n_in,
                              void* d_out, int out_size, void* d_ws, size_t ws_size,
                              hipStream_t stream)
{
    const float* A  = (const float*)d_in[0];
    const float* B  = (const float*)d_in[1];
    const int*   gt = (const int*)d_in[2];
    float* out = (float*)d_out;

    char* ws = (char*)d_ws;
    const size_t NB = (size_t)NROWS * DIM * sizeof(bf16_t); // 6,291,456
    bf16_t* Ab = (bf16_t*)(ws);
    bf16_t* Bb = (bf16_t*)(ws + NB);
    float* sa = (float*)(ws + 2 * NB);
    float* sb = (float*)(ws + 2 * NB + 16384);
    float* ra = (float*)(ws + 2 * NB + 32768);
    float* rb = (float*)(ws + 2 * NB + 49152);
    u64* gtp  = (u64*)(ws + 2 * NB + 65536); // 2 MB

    prologue_kernel<<<dim3(10240), 256, 0, stream>>>(
        A, B, gt, Ab, Bb, sa, sb, ra, rb, gtp, out);
    loss_kernel<<<dim3(1024), 256, 0, stream>>>(
        Ab, Bb, sa, sb, ra, rb, (const uint2*)gtp, out);
}

// Round 5
// 161.906 us; speedup vs baseline: 1.1307x; 1.1307x over previous
//
#include <hip/hip_runtime.h>
#include <hip/hip_bf16.h>
#include <stdint.h>
#include <stddef.h>

// ContrastiveLoss: N=4096, D=768.
// loss = mean_{ij} (1-g)*d2 + g*max(2-sqrt(d2),0)^2,
// d2 = sa[i]+sb[j]-2*dot(i,j)+2e-6*(ra[i]-rb[j])+768e-12 (clamped at 0).
// R4: revert to proven single-buffer 2-barrier K-loop (R2, 0 conflicts),
//     upgrade to 32x32x16 MFMA + 256x128 block tile (128x64 per wave):
//     2x FLOP/LDS-byte, +20% MFMA ceiling, fewer staging bytes.
//     launch_bounds(256,2): 128 AGPR acc + VGPRs fit in 256 (no spill —
//     R3's 100 MB WRITE_SIZE was scratch spill under the (256,4) cap).

#define NROWS 4096
#define DIM   768
#define BM    256
#define BN    128
#define BK    64
#define KITERS (DIM / BK)   // 12
#define MARGIN 2.0f
#define EPSV   1e-6f

typedef __bf16 bf16_t;
typedef bf16_t bf16x8 __attribute__((ext_vector_type(8)));
typedef bf16_t bf16x4 __attribute__((ext_vector_type(4)));
typedef float  f32x16 __attribute__((ext_vector_type(16)));
typedef unsigned long long u64;

// ---------------- prologue: prep (2048 blocks) + pack (8192 blocks) --------
__global__ __launch_bounds__(256) void prologue_kernel(
    const float* __restrict__ A, const float* __restrict__ B,
    const int* __restrict__ gt,
    bf16_t* __restrict__ Ab, bf16_t* __restrict__ Bb,
    float* __restrict__ sa, float* __restrict__ sb,
    float* __restrict__ ra, float* __restrict__ rb,
    u64* __restrict__ gtp, float* __restrict__ out)
{
    const int tid  = threadIdx.x;
    const int wave = tid >> 6;
    const int lane = tid & 63;
    const int bx   = blockIdx.x;

    if (bx == 0 && tid == 0) out[0] = 0.0f;

    if (bx < 2048) {
        // ---- prep: bf16 cast + exact fp32 row sums / sum-of-squares ----
        const int isB  = bx >= 1024;
        const int row  = (bx & 1023) * 4 + wave;
        const float* X = isB ? B : A;
        bf16_t* Xb     = isB ? Bb : Ab;
        float* sdst    = isB ? sb : sa;
        float* rdst    = isB ? rb : ra;

        const float4* xr = (const float4*)(X + (size_t)row * DIM);
        bf16x4* xb = (bf16x4*)(Xb + (size_t)row * DIM);

        float sum = 0.0f, sq = 0.0f;
        #pragma unroll
        for (int j = 0; j < 3; ++j) {
            float4 v = xr[lane + 64 * j];
            bf16x4 o;
            o[0] = (bf16_t)v.x; o[1] = (bf16_t)v.y;
            o[2] = (bf16_t)v.z; o[3] = (bf16_t)v.w;
            xb[lane + 64 * j] = o;
            sum += (v.x + v.y) + (v.z + v.w);
            sq  += v.x * v.x + v.y * v.y + v.z * v.z + v.w * v.w;
        }
        #pragma unroll
        for (int off = 32; off > 0; off >>= 1) {
            sum += __shfl_down(sum, off);
            sq  += __shfl_down(sq,  off);
        }
        if (lane == 0) { rdst[row] = sum; sdst[row] = sq; }
    } else {
        // ---- pack: gt int32 -> u64 bitmask per 64-col block ----
        const int wid = (bx - 2048) * 4 + wave;
        const size_t base = (size_t)wid * 8;
        int v[8];
        #pragma unroll
        for (int i = 0; i < 8; ++i)
            v[i] = gt[base * 64 + (size_t)i * 64 + lane];
        u64 mine = 0;
        #pragma unroll
        for (int i = 0; i < 8; ++i) {
            const u64 m = __ballot(v[i] != 0);
            if (lane == i) mine = m;
        }
        if (lane < 8) gtp[base + lane] = mine;
    }
}

// ---------------- fused GEMM + loss ----------------------------------------
// 256x128 block tile / 256 threads; wave-tile 128x64 = 4x2 of 32x32x16 MFMA.
// BK=64, single-buffered LDS (48 KB), proven 2-barrier loop, XOR-8 swizzle
// on 128-B rows (conflict-free ds_read_b128).
// A/B frag layout: elem row/col = lane&31, k = (lane>>5)*8 + j.
// C/D layout: col = lane&31, row = (reg&3) + 8*(reg>>2) + 4*(lane>>5).
__global__ __launch_bounds__(256, 2) void loss_kernel(
    const bf16_t* __restrict__ A, const bf16_t* __restrict__ B,
    const float* __restrict__ sa, const float* __restrict__ sb,
    const float* __restrict__ ra, const float* __restrict__ rb,
    const uint2* __restrict__ gtp, float* __restrict__ out)
{
    __shared__ __align__(16) bf16_t As[BM * BK];  // 32 KB
    __shared__ __align__(16) bf16_t Bs[BN * BK];  // 16 KB

    const int tid  = threadIdx.x;
    const int wave = tid >> 6;
    const int lane = tid & 63;
    const int m0 = (blockIdx.x >> 5) * BM;   // 16 m-tiles
    const int n0 = (blockIdx.x & 31) * BN;   // 32 n-tiles

    f32x16 acc[4][2] = {};

    const int cq = lane & 31;   // frag row (A) / col (B); also C col
    const int kh = lane >> 5;   // k-half selector
    const int wm = (wave >> 1) * 128;
    const int wn = (wave & 1) * 64;

    // staging lane constants: chunk c = c0 + lane; row = c>>3, slot p = c&7;
    // LDS slot p of row holds global chunk p ^ (row&7)   [XOR-8 swizzle]
    const int srow = lane >> 3;
    const int sp   = lane & 7;

    for (int k0 = 0; k0 < DIM; k0 += BK) {
        __syncthreads();   // prev iter's LDS reads done
        #pragma unroll
        for (int j = 0; j < 8; ++j) {          // A: 2048 chunks, 512/wave
            const int c0  = wave * 512 + j * 64;            // wave-uniform
            const int row = (c0 >> 3) + srow;
            const int gcx = sp ^ (row & 7);
            const bf16_t* ga = A + (size_t)(m0 + row) * DIM + k0 + gcx * 8;
            __builtin_amdgcn_global_load_lds(
                (const __attribute__((address_space(1))) void*)ga,
                (__attribute__((address_space(3))) void*)(As + c0 * 8),
                16, 0, 0);
        }
        #pragma unroll
        for (int j = 0; j < 4; ++j) {          // B: 1024 chunks, 256/wave
            const int c0  = wave * 256 + j * 64;
            const int row = (c0 >> 3) + srow;
            const int gcx = sp ^ (row & 7);
            const bf16_t* gb = B + (size_t)(n0 + row) * DIM + k0 + gcx * 8;
            __builtin_amdgcn_global_load_lds(
                (const __attribute__((address_space(1))) void*)gb,
                (__attribute__((address_space(3))) void*)(Bs + c0 * 8),
                16, 0, 0);
        }
        __syncthreads();   // staging complete

        #pragma unroll
        for (int ks = 0; ks < 4; ++ks) {       // K=16 steps within BK=64
            const int gk = ks * 2 + kh;        // this lane's 8-elem chunk
            bf16x8 af[4], bfr[2];
            #pragma unroll
            for (int mb = 0; mb < 4; ++mb) {
                const int row = wm + mb * 32 + cq;
                af[mb] = *(const bf16x8*)(As + row * BK + (gk ^ (row & 7)) * 8);
            }
            #pragma unroll
            for (int nb = 0; nb < 2; ++nb) {
                const int row = wn + nb * 32 + cq;
                bfr[nb] = *(const bf16x8*)(Bs + row * BK + (gk ^ (row & 7)) * 8);
            }
            #pragma unroll
            for (int mb = 0; mb < 4; ++mb)
                #pragma unroll
                for (int nb = 0; nb < 2; ++nb)
                    acc[mb][nb] = __builtin_amdgcn_mfma_f32_32x32x16_bf16(
                        af[mb], bfr[nb], acc[mb][nb], 0, 0, 0);
        }
    }

    // ---- fused epilogue ----
    // contrib = (1-g)*max(d2,0) + g*max(2-sqrt(max(d2,0)),0)^2.
    // Fast path (d2 >= 4 -> hinge==0): contrib = d2 - g*d2; exact slow path
    // guarded by running min(d2) (never taken for this data).
    const int cb = (n0 + wn) >> 6;   // u64 word index within row

    const float cc0 = sb[n0 + wn + cq]      - 2.0f * EPSV * rb[n0 + wn + cq];
    const float cc1 = sb[n0 + wn + 32 + cq] - 2.0f * EPSV * rb[n0 + wn + 32 + cq];

    float s_all = 0.0f, s_g = 0.0f, dmin = 1e30f;
    #pragma unroll
    for (int mb = 0; mb < 4; ++mb) {
        #pragma unroll
        for (int r = 0; r < 16; ++r) {
            const int row = m0 + wm + mb * 32 + 4 * kh + ((r & 3) + 8 * (r >> 2));
            const float crr = sa[row] + 2.0f * EPSV * ra[row]
                            + (float)DIM * EPSV * EPSV;
            const uint2 w = gtp[(size_t)row * (NROWS / 64) + cb];
            const float d2a = (crr + cc0) - 2.0f * acc[mb][0][r];
            const float d2b = (crr + cc1) - 2.0f * acc[mb][1][r];
            s_all += d2a + d2b;
            dmin = fminf(dmin, fminf(d2a, d2b));
            const float g0 = (float)((w.x >> cq) & 1u);
            const float g1 = (float)((w.y >> cq) & 1u);
            s_g = fmaf(g0, d2a, fmaf(g1, d2b, s_g));
        }
    }
    float local = s_all - s_g;

    if (dmin < 4.0f) {   // exact correction; never taken for this data
        #pragma unroll
        for (int mb = 0; mb < 4; ++mb) {
            #pragma unroll
            for (int r = 0; r < 16; ++r) {
                const int row = m0 + wm + mb * 32 + 4 * kh + ((r & 3) + 8 * (r >> 2));
                const float crr = sa[row] + 2.0f * EPSV * ra[row]
                                + (float)DIM * EPSV * EPSV;
                const uint2 w = gtp[(size_t)row * (NROWS / 64) + cb];
                #pragma unroll
                for (int nb = 0; nb < 2; ++nb) {
                    const float d2 = (crr + (nb ? cc1 : cc0))
                                   - 2.0f * acc[mb][nb][r];
                    if (d2 < 4.0f) {
                        const float gf = (float)(((nb ? w.y : w.x) >> cq) & 1u);
                        const float d2c  = fmaxf(d2, 0.0f);
                        const float dist = sqrtf(d2c);
                        const float h    = fmaxf(MARGIN - dist, 0.0f);
                        local += (1.0f - gf) * d2c + gf * h * h - (d2 - gf * d2);
                    }
                }
            }
        }
    }

    #pragma unroll
    for (int off = 32; off > 0; off >>= 1) local += __shfl_down(local, off);

    float* redp = (float*)As;   // reuse LDS for block reduction
    __syncthreads();
    if (lane == 0) redp[wave] = local;
    __syncthreads();
    if (tid == 0) {
        const float s = (redp[0] + redp[1]) + (redp[2] + redp[3]);
        atomicAdd(out, s * (1.0f / (4096.0f * 4096.0f)));
    }
}

// ---------------------------------------------------------------------------
extern "C" void kernel_launch(void* const* d_in, const int* in_sizes, int n_in,
                              void* d_out, int out_size, void* d_ws, size_t ws_size,
                              hipStream_t stream)
{
    const float* A  = (const float*)d_in[0];
    const float* B  = (const float*)d_in[1];
    const int*   gt = (const int*)d_in[2];
    float* out = (float*)d_out;

    char* ws = (char*)d_ws;
    const size_t NB = (size_t)NROWS * DIM * sizeof(bf16_t); // 6,291,456
    bf16_t* Ab = (bf16_t*)(ws);
    bf16_t* Bb = (bf16_t*)(ws + NB);
    float* sa = (float*)(ws + 2 * NB);
    float* sb = (float*)(ws + 2 * NB + 16384);
    float* ra = (float*)(ws + 2 * NB + 32768);
    float* rb = (float*)(ws + 2 * NB + 49152);
    u64* gtp  = (u64*)(ws + 2 * NB + 65536); // 2 MB

    prologue_kernel<<<dim3(10240), 256, 0, stream>>>(
        A, B, gt, Ab, Bb, sa, sb, ra, rb, gtp, out);
    loss_kernel<<<dim3((NROWS / BM) * (NROWS / BN)), 256, 0, stream>>>(
        Ab, Bb, sa, sb, ra, rb, (const uint2*)gtp, out);
}

// Round 6
// 155.551 us; speedup vs baseline: 1.1768x; 1.0409x over previous
//
#include <hip/hip_runtime.h>
#include <hip/hip_bf16.h>
#include <stdint.h>
#include <stddef.h>

// ContrastiveLoss: N=4096, D=768.
// loss = mean_{ij} (1-g)*d2 + g*max(2-sqrt(d2),0)^2,
// d2 = sa[i]+sb[j]-2*dot(i,j)+2e-6*(ra[i]-rb[j])+768e-12 (clamped at 0).
// R5: R2's proven loss structure (128x128 tile, 16x16x32 MFMA, XOR-8 swizzle,
//     2-barrier K-loop — 0 conflicts, 0 spill) ported to fp8 e4m3:
//     half LDS/staging bytes, BK=128 elems -> 6 K-iters (half the barriers).
//     Exact fp32 row stats keep accuracy; only dot is quantized (unbiased).
//     Cheap hinge-free epilogue fast path (validated R3/R4, absmax 0).
// Lesson log: 32x32 frag pattern = structural 4-way LDS conflict (R4);
//     dbuf @ (256,4) = spill, WRITE_SIZE is the spill detector (R3).

#define NROWS 4096
#define DIM   768
#define BM    128
#define BN    128
#define BKE   128              // K elements per tile (= 128 bytes fp8)
#define KITERS (DIM / BKE)     // 6
#define MARGIN 2.0f
#define EPSV   1e-6f

typedef float f32x4 __attribute__((ext_vector_type(4)));
typedef unsigned long long u64;
typedef unsigned char fp8_t;

// ---------------- prologue: prep (2048 blocks) + pack (8192 blocks) --------
__global__ __launch_bounds__(256) void prologue_kernel(
    const float* __restrict__ A, const float* __restrict__ B,
    const int* __restrict__ gt,
    fp8_t* __restrict__ Af8, fp8_t* __restrict__ Bf8,
    float* __restrict__ sa, float* __restrict__ sb,
    float* __restrict__ ra, float* __restrict__ rb,
    u64* __restrict__ gtp, float* __restrict__ out)
{
    const int tid  = threadIdx.x;
    const int wave = tid >> 6;
    const int lane = tid & 63;
    const int bx   = blockIdx.x;

    if (bx == 0 && tid == 0) out[0] = 0.0f;

    if (bx < 2048) {
        // ---- prep: fp8 cast + exact fp32 row sums / sum-of-squares ----
        const int isB  = bx >= 1024;
        const int row  = (bx & 1023) * 4 + wave;
        const float* X = isB ? B : A;
        fp8_t* Xb      = isB ? Bf8 : Af8;
        float* sdst    = isB ? sb : sa;
        float* rdst    = isB ? rb : ra;

        const float4* xr = (const float4*)(X + (size_t)row * DIM);
        unsigned int* xb = (unsigned int*)(Xb + (size_t)row * DIM);

        float sum = 0.0f, sq = 0.0f;
        #pragma unroll
        for (int j = 0; j < 3; ++j) {
            float4 v = xr[lane + 64 * j];
            int pk = 0;
            pk = __builtin_amdgcn_cvt_pk_fp8_f32(v.x, v.y, pk, false);
            pk = __builtin_amdgcn_cvt_pk_fp8_f32(v.z, v.w, pk, true);
            xb[lane + 64 * j] = (unsigned int)pk;
            sum += (v.x + v.y) + (v.z + v.w);
            sq  += v.x * v.x + v.y * v.y + v.z * v.z + v.w * v.w;
        }
        #pragma unroll
        for (int off = 32; off > 0; off >>= 1) {
            sum += __shfl_down(sum, off);
            sq  += __shfl_down(sq,  off);
        }
        if (lane == 0) { rdst[row] = sum; sdst[row] = sq; }
    } else {
        // ---- pack: gt int32 -> u64 bitmask per 64-col block ----
        const int wid = (bx - 2048) * 4 + wave;
        const size_t base = (size_t)wid * 8;
        int v[8];
        #pragma unroll
        for (int i = 0; i < 8; ++i)
            v[i] = gt[base * 64 + (size_t)i * 64 + lane];
        u64 mine = 0;
        #pragma unroll
        for (int i = 0; i < 8; ++i) {
            const u64 m = __ballot(v[i] != 0);
            if (lane == i) mine = m;
        }
        if (lane < 8) gtp[base + lane] = mine;
    }
}

// ---------------- fused GEMM + loss (fp8 e4m3) ------------------------------
// 128x128 tile / 256 threads (4 waves x 64x64 of 4x4 16x16x32 fp8 MFMA).
// BKE=128 elems = 128-B rows; single-buffered LDS (32 KB), 2-barrier loop,
// XOR-8 swizzle on 16-B chunks (R2's proven conflict-free pattern: 16 rows
// x 4 k-quads per 16-lane group). Frag reads are ds_read_b64 (8 fp8).
// A/B frag element layout (dtype-independent, = bf16 16x16x32):
//   row/col = lane&15, k = (lane>>4)*8 + j  within each K=32 window.
// C/D layout: col = lane&15, row = (lane>>4)*4 + reg.
__global__ __launch_bounds__(256, 4) void loss_kernel(
    const fp8_t* __restrict__ A, const fp8_t* __restrict__ B,
    const float* __restrict__ sa, const float* __restrict__ sb,
    const float* __restrict__ ra, const float* __restrict__ rb,
    const uint2* __restrict__ gtp, float* __restrict__ out)
{
    __shared__ __align__(16) fp8_t As[BM * BKE];  // 16 KB
    __shared__ __align__(16) fp8_t Bs[BN * BKE];  // 16 KB

    const int tid  = threadIdx.x;
    const int wave = tid >> 6;
    const int lane = tid & 63;
    const int m0 = blockIdx.y * BM;
    const int n0 = blockIdx.x * BN;

    f32x4 acc[4][4] = {};

    const int fr = lane & 15;            // frag row (A) / frag col (B)
    const int q  = lane >> 4;            // k-quad within each K=32 window
    const int wm = (wave >> 1) * 64;
    const int wn = (wave & 1) * 64;

    // staging: chunk c (16 B) -> row c>>3, slot c&7; LDS slot p of row holds
    // global chunk p ^ (row&7)   [XOR-8 swizzle]
    const int srow = lane >> 3;
    const int sp   = lane & 7;

    for (int k0 = 0; k0 < DIM; k0 += BKE) {
        __syncthreads();   // prev iter's LDS reads done
        #pragma unroll
        for (int j = 0; j < 4; ++j) {          // A: 1024 chunks, 256/wave
            const int c0  = wave * 256 + j * 64;            // wave-uniform
            const int row = (c0 >> 3) + srow;
            const int gcx = sp ^ (row & 7);
            const fp8_t* ga = A + (size_t)(m0 + row) * DIM + k0 + gcx * 16;
            __builtin_amdgcn_global_load_lds(
                (const __attribute__((address_space(1))) void*)ga,
                (__attribute__((address_space(3))) void*)(As + c0 * 16),
                16, 0, 0);
        }
        #pragma unroll
        for (int j = 0; j < 4; ++j) {          // B: 1024 chunks, 256/wave
            const int c0  = wave * 256 + j * 64;
            const int row = (c0 >> 3) + srow;
            const int gcx = sp ^ (row & 7);
            const fp8_t* gb = B + (size_t)(n0 + row) * DIM + k0 + gcx * 16;
            __builtin_amdgcn_global_load_lds(
                (const __attribute__((address_space(1))) void*)gb,
                (__attribute__((address_space(3))) void*)(Bs + c0 * 16),
                16, 0, 0);
        }
        __syncthreads();   // staging complete

        #pragma unroll
        for (int kk = 0; kk < 4; ++kk) {       // four K=32 windows in BKE
            // lane's 8-B granule g = kk*4 + q; chunk c = g>>1, half h = g&1
            const int c = kk * 2 + (q >> 1);
            const int h = (q & 1) * 8;
            long af[4], bfr[4];
            #pragma unroll
            for (int i = 0; i < 4; ++i) {
                const int ra_ = wm + i * 16 + fr;
                const int rb_ = wn + i * 16 + fr;
                af[i]  = *(const long*)(As + ra_ * BKE + (c ^ (ra_ & 7)) * 16 + h);
                bfr[i] = *(const long*)(Bs + rb_ * BKE + (c ^ (rb_ & 7)) * 16 + h);
            }
            #pragma unroll
            for (int mi = 0; mi < 4; ++mi)
                #pragma unroll
                for (int ni = 0; ni < 4; ++ni)
                    acc[mi][ni] = __builtin_amdgcn_mfma_f32_16x16x32_fp8_fp8(
                        af[mi], bfr[ni], acc[mi][ni], 0, 0, 0);
        }
    }

    // ---- fused epilogue: C/D col=lane&15, row=(lane>>4)*4+reg ----
    // Fast path (d2 >= 4 -> hinge==0): contrib = d2 - g*d2; exact slow path
    // guarded by running min(d2) (never taken for this data).
    const int cq = lane & 15;
    const int rq = (lane >> 4) * 4;
    const int cb = (n0 + wn) >> 6;

    float cc[4];
    #pragma unroll
    for (int ni = 0; ni < 4; ++ni) {
        const int col = n0 + wn + ni * 16 + cq;
        cc[ni] = sb[col] - 2.0f * EPSV * rb[col];
    }

    float s_all = 0.0f, s_g = 0.0f, dmin = 1e30f;
    #pragma unroll
    for (int mi = 0; mi < 4; ++mi) {
        #pragma unroll
        for (int rr = 0; rr < 4; ++rr) {
            const int row = m0 + wm + mi * 16 + rq + rr;
            const float crr = sa[row] + 2.0f * EPSV * ra[row]
                            + (float)DIM * EPSV * EPSV;
            const uint2 w = gtp[(size_t)row * (NROWS / 64) + cb];
            #pragma unroll
            for (int ni = 0; ni < 4; ++ni) {
                const float d2 = (crr + cc[ni]) - 2.0f * acc[mi][ni][rr];
                s_all += d2;
                dmin = fminf(dmin, d2);
                const unsigned wd = (ni < 2) ? w.x : w.y;
                const float gf = (float)((wd >> (cq + (ni & 1) * 16)) & 1u);
                s_g = fmaf(gf, d2, s_g);
            }
        }
    }
    float local = s_all - s_g;

    if (dmin < 4.0f) {   // exact correction; never taken for this data
        #pragma unroll
        for (int mi = 0; mi < 4; ++mi) {
            #pragma unroll
            for (int rr = 0; rr < 4; ++rr) {
                const int row = m0 + wm + mi * 16 + rq + rr;
                const float crr = sa[row] + 2.0f * EPSV * ra[row]
                                + (float)DIM * EPSV * EPSV;
                const uint2 w = gtp[(size_t)row * (NROWS / 64) + cb];
                #pragma unroll
                for (int ni = 0; ni < 4; ++ni) {
                    const float d2 = (crr + cc[ni]) - 2.0f * acc[mi][ni][rr];
                    if (d2 < 4.0f) {
                        const unsigned wd = (ni < 2) ? w.x : w.y;
                        const float gf = (float)((wd >> (cq + (ni & 1) * 16)) & 1u);
                        const float d2c  = fmaxf(d2, 0.0f);
                        const float dist = sqrtf(d2c);
                        const float h    = fmaxf(MARGIN - dist, 0.0f);
                        local += (1.0f - gf) * d2c + gf * h * h - (d2 - gf * d2);
                    }
                }
            }
        }
    }

    #pragma unroll
    for (int off = 32; off > 0; off >>= 1) local += __shfl_down(local, off);

    float* redp = (float*)As;   // reuse LDS for block reduction
    __syncthreads();
    if (lane == 0) redp[wave] = local;
    __syncthreads();
    if (tid == 0) {
        const float s = (redp[0] + redp[1]) + (redp[2] + redp[3]);
        atomicAdd(out, s * (1.0f / (4096.0f * 4096.0f)));
    }
}

// ---------------------------------------------------------------------------
extern "C" void kernel_launch(void* const* d_in, const int* in_sizes, int n_in,
                              void* d_out, int out_size, void* d_ws, size_t ws_size,
                              hipStream_t stream)
{
    const float* A  = (const float*)d_in[0];
    const float* B  = (const float*)d_in[1];
    const int*   gt = (const int*)d_in[2];
    float* out = (float*)d_out;

    char* ws = (char*)d_ws;
    const size_t NB8 = (size_t)NROWS * DIM;   // 3,145,728 bytes per fp8 matrix
    fp8_t* Af8 = (fp8_t*)(ws);
    fp8_t* Bf8 = (fp8_t*)(ws + NB8);
    float* sa = (float*)(ws + 2 * NB8);
    float* sb = (float*)(ws + 2 * NB8 + 16384);
    float* ra = (float*)(ws + 2 * NB8 + 32768);
    float* rb = (float*)(ws + 2 * NB8 + 49152);
    u64* gtp  = (u64*)(ws + 2 * NB8 + 65536); // 2 MB

    prologue_kernel<<<dim3(10240), 256, 0, stream>>>(
        A, B, gt, Af8, Bf8, sa, sb, ra, rb, gtp, out);
    loss_kernel<<<dim3(NROWS / BN, NROWS / BM), 256, 0, stream>>>(
        Af8, Bf8, sa, sb, ra, rb, (const uint2*)gtp, out);
}

// Round 7
// 135.536 us; speedup vs baseline: 1.3506x; 1.1477x over previous
//
#include <hip/hip_runtime.h>
#include <hip/hip_bf16.h>
#include <stdint.h>
#include <stddef.h>

// ContrastiveLoss: N=4096, D=768.
// loss = mean_{ij} (1-g)*d2 + g*max(2-sqrt(d2),0)^2,
// d2 = sa[i]+sb[j]-2*dot(i,j)+2e-6*(ra[i]-rb[j])+768e-12 (clamped at 0).
// R6: fp8 e4m3 GEMM with a k-permuted global layout so the LDS frag reads
//     replicate R2's ONLY-proven-conflict-free pattern (16 rows x 4
//     consecutive 16-B chunks, XOR-8 over rows, ds_read_b128). Epilogue
//     de-duplicated (per-element rare branch) to kill the acc->scratch spill
//     (R4/R5: WRITE_SIZE 13/59 MB from dup slow-path; R2 single pass: 32 B).
// Lesson log: R4 32x32 frags = structural 4-way conflict; R3 dbuf = spill;
//     WRITE_SIZE is the spill detector; only R2's LDS algebra measures 0.

#define NROWS 4096
#define DIM   768
#define BM    128
#define BN    128
#define BKE   128              // K elements per tile (128 B fp8 rows)
#define MARGIN 2.0f
#define EPSV   1e-6f

typedef float f32x4 __attribute__((ext_vector_type(4)));
typedef long  lng2  __attribute__((ext_vector_type(2)));
typedef unsigned long long u64;
typedef unsigned char fp8_t;

// Permutation of each 128-elem k-segment, baked into the fp8 global layout:
// element (kk,q,j) [kk=K32-window 0..3, q=quad 0..3, j=0..7] is stored at
// byte ((kk>>1)*4 + q)*16 + (kk&1)*8 + j. Both A and B use it => dot
// products are unchanged (same k-order on both operands).

// ---------------- prologue: prep (2048 blocks) + pack (8192 blocks) --------
__global__ __launch_bounds__(256) void prologue_kernel(
    const float* __restrict__ A, const float* __restrict__ B,
    const int* __restrict__ gt,
    fp8_t* __restrict__ Af8, fp8_t* __restrict__ Bf8,
    float* __restrict__ sa, float* __restrict__ sb,
    float* __restrict__ ra, float* __restrict__ rb,
    u64* __restrict__ gtp, float* __restrict__ out)
{
    const int tid  = threadIdx.x;
    const int wave = tid >> 6;
    const int lane = tid & 63;
    const int bx   = blockIdx.x;

    if (bx == 0 && tid == 0) out[0] = 0.0f;

    if (bx < 2048) {
        // ---- prep: fp8 cast (k-permuted) + exact fp32 row sums/sumsq ----
        const int isB  = bx >= 1024;
        const int row  = (bx & 1023) * 4 + wave;
        const float* X = isB ? B : A;
        fp8_t* Xb      = isB ? Bf8 : Af8;
        float* sdst    = isB ? sb : sa;
        float* rdst    = isB ? rb : ra;

        const float4* xr = (const float4*)(X + (size_t)row * DIM);
        unsigned int* xb = (unsigned int*)(Xb + (size_t)row * DIM);

        float sum = 0.0f, sq = 0.0f;
        #pragma unroll
        for (int jb = 0; jb < 3; ++jb) {
            float4 v = xr[lane + 64 * jb];
            int pk = 0;
            pk = __builtin_amdgcn_cvt_pk_fp8_f32(v.x, v.y, pk, false);
            pk = __builtin_amdgcn_cvt_pk_fp8_f32(v.z, v.w, pk, true);
            // permuted destination dword
            const int e4  = lane + 64 * jb;     // source dword idx in row
            const int seg = e4 >> 5;            // 128-elem segment
            const int e   = (e4 & 31) * 4;      // elem within segment
            const int kk  = e >> 5;
            const int q   = (e >> 3) & 3;
            const int jj  = e & 7;              // 0 or 4
            const int pos = ((kk >> 1) * 4 + q) * 16 + (kk & 1) * 8 + jj;
            xb[seg * 32 + (pos >> 2)] = (unsigned int)pk;
            sum += (v.x + v.y) + (v.z + v.w);
            sq  += v.x * v.x + v.y * v.y + v.z * v.z + v.w * v.w;
        }
        #pragma unroll
        for (int off = 32; off > 0; off >>= 1) {
            sum += __shfl_down(sum, off);
            sq  += __shfl_down(sq,  off);
        }
        if (lane == 0) { rdst[row] = sum; sdst[row] = sq; }
    } else {
        // ---- pack: gt int32 -> u64 bitmask per 64-col block ----
        const int wid = (bx - 2048) * 4 + wave;
        const size_t base = (size_t)wid * 8;
        int v[8];
        #pragma unroll
        for (int i = 0; i < 8; ++i)
            v[i] = gt[base * 64 + (size_t)i * 64 + lane];
        u64 mine = 0;
        #pragma unroll
        for (int i = 0; i < 8; ++i) {
            const u64 m = __ballot(v[i] != 0);
            if (lane == i) mine = m;
        }
        if (lane < 8) gtp[base + lane] = mine;
    }
}

// ---------------- fused GEMM + loss (fp8 e4m3, k-permuted layout) ----------
// 128x128 tile / 256 threads (4 waves x 64x64 of 4x4 16x16x32 fp8 MFMA).
// BKE=128 (128-B LDS rows), single-buffered 32 KB LDS, 2-barrier K-loop.
// Frag reads: b128 at chunk c = kk2*4 + q, slot (c ^ (row&7)) — R2's
// measured-conflict-free algebra. Each b128 = windows 2*kk2 (lo 8 B) and
// 2*kk2+1 (hi 8 B).
__global__ __launch_bounds__(256, 4) void loss_kernel(
    const fp8_t* __restrict__ A, const fp8_t* __restrict__ B,
    const float* __restrict__ sa, const float* __restrict__ sb,
    const float* __restrict__ ra, const float* __restrict__ rb,
    const uint2* __restrict__ gtp, float* __restrict__ out)
{
    __shared__ __align__(16) fp8_t As[BM * BKE];  // 16 KB
    __shared__ __align__(16) fp8_t Bs[BN * BKE];  // 16 KB

    const int tid  = threadIdx.x;
    const int wave = tid >> 6;
    const int lane = tid & 63;
    const int m0 = blockIdx.y * BM;
    const int n0 = blockIdx.x * BN;

    f32x4 acc[4][4] = {};

    const int fr = lane & 15;            // frag row (A) / frag col (B)
    const int q  = lane >> 4;            // quad
    const int wm = (wave >> 1) * 64;
    const int wn = (wave & 1) * 64;

    // staging: chunk c (16 B) -> row c>>3, slot c&7; LDS slot p of row holds
    // global chunk p ^ (row&7)   [XOR-8 swizzle]
    const int srow = lane >> 3;
    const int sp   = lane & 7;

    for (int k0 = 0; k0 < DIM; k0 += BKE) {
        __syncthreads();   // prev iter's LDS reads done
        #pragma unroll
        for (int j = 0; j < 4; ++j) {          // A: 1024 chunks, 256/wave
            const int c0  = wave * 256 + j * 64;            // wave-uniform
            const int row = (c0 >> 3) + srow;
            const int gcx = sp ^ (row & 7);
            const fp8_t* ga = A + (size_t)(m0 + row) * DIM + k0 + gcx * 16;
            __builtin_amdgcn_global_load_lds(
                (const __attribute__((address_space(1))) void*)ga,
                (__attribute__((address_space(3))) void*)(As + c0 * 16),
                16, 0, 0);
        }
        #pragma unroll
        for (int j = 0; j < 4; ++j) {          // B: 1024 chunks, 256/wave
            const int c0  = wave * 256 + j * 64;
            const int row = (c0 >> 3) + srow;
            const int gcx = sp ^ (row & 7);
            const fp8_t* gb = B + (size_t)(n0 + row) * DIM + k0 + gcx * 16;
            __builtin_amdgcn_global_load_lds(
                (const __attribute__((address_space(1))) void*)gb,
                (__attribute__((address_space(3))) void*)(Bs + c0 * 16),
                16, 0, 0);
        }
        __syncthreads();   // staging complete

        #pragma unroll
        for (int kk2 = 0; kk2 < 2; ++kk2) {    // each step: 2 K=32 windows
            const int c = kk2 * 4 + q;         // consecutive chunk per quad
            lng2 ap[4], bp[4];
            #pragma unroll
            for (int i = 0; i < 4; ++i) {
                const int ar = wm + i * 16 + fr;
                const int br = wn + i * 16 + fr;
                ap[i] = *(const lng2*)(As + ar * BKE + ((c ^ (ar & 7)) * 16));
                bp[i] = *(const lng2*)(Bs + br * BKE + ((c ^ (br & 7)) * 16));
            }
            #pragma unroll
            for (int mi = 0; mi < 4; ++mi)
                #pragma unroll
                for (int ni = 0; ni < 4; ++ni)
                    acc[mi][ni] = __builtin_amdgcn_mfma_f32_16x16x32_fp8_fp8(
                        ap[mi][0], bp[ni][0], acc[mi][ni], 0, 0, 0);
            #pragma unroll
            for (int mi = 0; mi < 4; ++mi)
                #pragma unroll
                for (int ni = 0; ni < 4; ++ni)
                    acc[mi][ni] = __builtin_amdgcn_mfma_f32_16x16x32_fp8_fp8(
                        ap[mi][1], bp[ni][1], acc[mi][ni], 0, 0, 0);
        }
    }

    // ---- fused epilogue: C/D col=lane&15, row=(lane>>4)*4+reg ----
    // Single traversal; per-element exact correction branch (never taken for
    // this data: min d2 ~ 1250 >> 4) — no dup loop, no spill trigger.
    const int cq = lane & 15;
    const int rq = (lane >> 4) * 4;
    const int cb = (n0 + wn) >> 6;

    float cc[4];
    #pragma unroll
    for (int ni = 0; ni < 4; ++ni) {
        const int col = n0 + wn + ni * 16 + cq;
        cc[ni] = sb[col] - 2.0f * EPSV * rb[col];
    }

    float local = 0.0f;
    #pragma unroll
    for (int mi = 0; mi < 4; ++mi) {
        #pragma unroll
        for (int rr = 0; rr < 4; ++rr) {
            const int row = m0 + wm + mi * 16 + rq + rr;
            const float crr = sa[row] + 2.0f * EPSV * ra[row]
                            + (float)DIM * EPSV * EPSV;
            const uint2 w = gtp[(size_t)row * (NROWS / 64) + cb];
            #pragma unroll
            for (int ni = 0; ni < 4; ++ni) {
                const float d2 = (crr + cc[ni]) - 2.0f * acc[mi][ni][rr];
                const unsigned wd = (ni < 2) ? w.x : w.y;
                const float gf = (float)((wd >> (cq + (ni & 1) * 16)) & 1u);
                float contrib = d2 - gf * d2;           // hinge==0 fast path
                if (__builtin_expect(d2 < 4.0f, 0)) {   // exact, never taken
                    const float d2c  = fmaxf(d2, 0.0f);
                    const float dist = sqrtf(d2c);
                    const float h    = fmaxf(MARGIN - dist, 0.0f);
                    contrib = (1.0f - gf) * d2c + gf * h * h;
                }
                local += contrib;
            }
        }
    }

    #pragma unroll
    for (int off = 32; off > 0; off >>= 1) local += __shfl_down(local, off);

    float* redp = (float*)As;   // reuse LDS for block reduction
    __syncthreads();
    if (lane == 0) redp[wave] = local;
    __syncthreads();
    if (tid == 0) {
        const float s = (redp[0] + redp[1]) + (redp[2] + redp[3]);
        atomicAdd(out, s * (1.0f / (4096.0f * 4096.0f)));
    }
}

// ---------------------------------------------------------------------------
extern "C" void kernel_launch(void* const* d_in, const int* in_sizes, int n_in,
                              void* d_out, int out_size, void* d_ws, size_t ws_size,
                              hipStream_t stream)
{
    const float* A  = (const float*)d_in[0];
    const float* B  = (const float*)d_in[1];
    const int*   gt = (const int*)d_in[2];
    float* out = (float*)d_out;

    char* ws = (char*)d_ws;
    const size_t NB8 = (size_t)NROWS * DIM;   // 3,145,728 B per fp8 matrix
    fp8_t* Af8 = (fp8_t*)(ws);
    fp8_t* Bf8 = (fp8_t*)(ws + NB8);
    float* sa = (float*)(ws + 2 * NB8);
    float* sb = (float*)(ws + 2 * NB8 + 16384);
    float* ra = (float*)(ws + 2 * NB8 + 32768);
    float* rb = (float*)(ws + 2 * NB8 + 49152);
    u64* gtp  = (u64*)(ws + 2 * NB8 + 65536); // 2 MB

    prologue_kernel<<<dim3(10240), 256, 0, stream>>>(
        A, B, gt, Af8, Bf8, sa, sb, ra, rb, gtp, out);
    loss_kernel<<<dim3(NROWS / BN, NROWS / BM), 256, 0, stream>>>(
        Af8, Bf8, sa, sb, ra, rb, (const uint2*)gtp, out);
}